// Round 1
// baseline (1860.549 us; speedup 1.0000x reference)
//
#include <hip/hip_runtime.h>
#include <math.h>

// ---------------- problem constants ----------------
#define N_NODES 100000
#define N_EDGES 400000
#define IN_CH   100
#define OUT_CH  100
#define HEADS   2
#define HC      200      // HEADS*OUT_CH
#define TIME_DIM 100
#define MSG_DIM  100
#define EDGE_DIM 200
// padded GEMM dims
#define KP_NODE 128      // IN_CH padded to mult of 32
#define KP_EDGE 224      // EDGE_DIM padded to mult of 32
#define NP_EDGE 208      // HC padded to mult of 16 (13 n-tiles)
#define N4      800      // 4*HC combined output cols [q|k|v|skip]

typedef __attribute__((ext_vector_type(8))) short bf16x8_t;
typedef __attribute__((ext_vector_type(4))) float f32x4_t;

struct __align__(8) us4 { unsigned short x, y, z, w; };

static __device__ __forceinline__ float b2f(unsigned short u){
  union { float f; unsigned int i; } v; v.i = ((unsigned int)u) << 16; return v.f;
}
static __device__ __forceinline__ unsigned short f2b(float f){
  union { float f; unsigned int i; } v; v.f = f;
  unsigned int x = v.i;
  return (unsigned short)((x + 0x7fffu + ((x >> 16) & 1u)) >> 16);
}

// ---------------- pack weights (bf16, transposed so B-fragments are 16B contiguous) ----
__global__ __launch_bounds__(256) void pack_weights(
    const float* __restrict__ Wq, const float* __restrict__ bq,
    const float* __restrict__ Wk, const float* __restrict__ bk,
    const float* __restrict__ Wv, const float* __restrict__ bv,
    const float* __restrict__ We, const float* __restrict__ Ws, const float* __restrict__ bs,
    unsigned short* __restrict__ W4T, unsigned short* __restrict__ WeT,
    float* __restrict__ bias4)
{
  int idx = blockIdx.x * 256 + threadIdx.x;
  if (idx < N4 * KP_NODE) {                    // W4T[c][k], c in [0,800)
    int c = idx / KP_NODE, k = idx % KP_NODE;
    int sel = c / HC, col = c % HC;
    float v = 0.f;
    if (k < IN_CH) {
      const float* W = (sel == 0) ? Wq : (sel == 1) ? Wk : (sel == 2) ? Wv : Ws;
      v = W[k * HC + col];
    }
    W4T[idx] = f2b(v);
    return;
  }
  int j = idx - N4 * KP_NODE;
  if (j < NP_EDGE * KP_EDGE) {                 // WeT[n][k]
    int n = j / KP_EDGE, k = j % KP_EDGE;
    float v = 0.f;
    if (n < HC && k < EDGE_DIM) v = We[k * HC + n];
    WeT[j] = f2b(v);
    return;
  }
  j -= NP_EDGE * KP_EDGE;
  if (j < N4) {
    int sel = j / HC, col = j % HC;
    const float* B = (sel == 0) ? bq : (sel == 1) ? bk : (sel == 2) ? bv : bs;
    bias4[j] = B[col];
  }
}

// ---------------- node GEMM: [16 nodes] x [100k] @ [100x800] -> q,k,v (bf16 ws), skip (fp32 out)
__global__ __launch_bounds__(256) void node_gemm(
    const float* __restrict__ x, const unsigned short* __restrict__ W4T,
    const float* __restrict__ bias4,
    unsigned short* __restrict__ q_b, unsigned short* __restrict__ k_b,
    unsigned short* __restrict__ v_b, float* __restrict__ out)
{
  __shared__ __align__(16) unsigned short x_tile[16 * 136]; // stride 136 avoids bank conflicts
  const int tid = threadIdx.x;
  const int n0 = blockIdx.x * 16;

  for (int idx = tid; idx < 16 * KP_NODE; idx += 256) {
    int r = idx >> 7, k = idx & 127;
    float v = (k < IN_CH) ? x[(n0 + r) * IN_CH + k] : 0.f;
    x_tile[r * 136 + k] = f2b(v);
  }
  __syncthreads();

  const int lane = tid & 63, wave = tid >> 6;
  const int m16 = lane & 15, quad = lane >> 4;

  f32x4_t acc[13];
  #pragma unroll
  for (int i = 0; i < 13; i++) acc[i] = (f32x4_t){0.f, 0.f, 0.f, 0.f};

  for (int kc = 0; kc < 4; kc++) {
    bf16x8_t a = *reinterpret_cast<const bf16x8_t*>(&x_tile[m16 * 136 + kc * 32 + quad * 8]);
    int i = 0;
    for (int nt = wave; nt < 50; nt += 4, i++) {
      bf16x8_t b = *reinterpret_cast<const bf16x8_t*>(
          &W4T[(nt * 16 + m16) * KP_NODE + kc * 32 + quad * 8]);
      acc[i] = __builtin_amdgcn_mfma_f32_16x16x32_bf16(a, b, acc[i], 0, 0, 0);
    }
  }

  int i = 0;
  for (int nt = wave; nt < 50; nt += 4, i++) {
    int c = nt * 16 + m16;
    float bias = bias4[c];
    #pragma unroll
    for (int r = 0; r < 4; r++) {
      int node = n0 + quad * 4 + r;
      float v = acc[i][r] + bias;
      if (c < 200)      q_b[(size_t)node * HC + c]        = f2b(v);
      else if (c < 400) k_b[(size_t)node * HC + (c - 200)] = f2b(v);
      else if (c < 600) v_b[(size_t)node * HC + (c - 400)] = f2b(v);
      else              out[(size_t)node * HC + (c - 600)] = v;
    }
  }
}

// ---------------- edge kernel: t_enc -> edge_attr -> e = edge_attr@We -> alpha/exp/denom, v_e
__global__ __launch_bounds__(256) void edge_gemm(
    const int* __restrict__ edge_index, const float* __restrict__ t,
    const float* __restrict__ last_update, const float* __restrict__ msg,
    const float* __restrict__ w_time, const float* __restrict__ b_time,
    const unsigned short* __restrict__ WeT,
    const unsigned short* __restrict__ q_b, const unsigned short* __restrict__ k_b,
    const unsigned short* __restrict__ v_b,
    unsigned short* __restrict__ v_e, float* __restrict__ exbuf,
    float* __restrict__ denom)
{
  // one buffer, time-multiplexed: phase 1 = edge_attr bf16 [64][232], phase 2 = e fp32 [64][209]
  __shared__ __align__(16) float e_smem[64 * 209];
  __shared__ int   src_s[64], dst_s[64];
  __shared__ float rel_s[64], wt_s[TIME_DIM], bt_s[TIME_DIM];
  unsigned short* ea = (unsigned short*)e_smem;

  const int tid = threadIdx.x;
  const int e0 = blockIdx.x * 64;

  if (tid < 64) {
    int e = e0 + tid;
    int s = edge_index[e], d = edge_index[N_EDGES + e];
    src_s[tid] = s; dst_s[tid] = d;
    rel_s[tid] = fabsf(last_update[s] - t[e]);
  } else if (tid < 64 + TIME_DIM) {
    int j = tid - 64; wt_s[j] = w_time[j]; bt_s[j] = b_time[j];
  }
  __syncthreads();

  // stage edge_attr tile (bf16) : cols 0..99 = cos(rel*w+b), 100..199 = msg, 200..223 = 0
  for (int idx = tid; idx < 64 * KP_EDGE; idx += 256) {
    int el = idx / KP_EDGE, k = idx % KP_EDGE;
    float v;
    if (k < TIME_DIM)      v = cosf(rel_s[el] * wt_s[k] + bt_s[k]);
    else if (k < EDGE_DIM) v = msg[(size_t)(e0 + el) * MSG_DIM + (k - TIME_DIM)];
    else                   v = 0.f;
    ea[el * 232 + k] = f2b(v);
  }
  __syncthreads();

  const int lane = tid & 63, wave = tid >> 6;
  const int m16 = lane & 15, quad = lane >> 4;

  f32x4_t acc[13];
  #pragma unroll
  for (int i = 0; i < 13; i++) acc[i] = (f32x4_t){0.f, 0.f, 0.f, 0.f};

  for (int kc = 0; kc < 7; kc++) {
    bf16x8_t a = *reinterpret_cast<const bf16x8_t*>(
        &ea[(wave * 16 + m16) * 232 + kc * 32 + quad * 8]);
    #pragma unroll
    for (int nt = 0; nt < 13; nt++) {
      bf16x8_t b = *reinterpret_cast<const bf16x8_t*>(
          &WeT[(nt * 16 + m16) * KP_EDGE + kc * 32 + quad * 8]);
      acc[nt] = __builtin_amdgcn_mfma_f32_16x16x32_bf16(a, b, acc[nt], 0, 0, 0);
    }
  }
  __syncthreads();   // everyone done reading ea before overwrite

  #pragma unroll
  for (int nt = 0; nt < 13; nt++) {
    #pragma unroll
    for (int r = 0; r < 4; r++) {
      e_smem[(wave * 16 + quad * 4 + r) * 209 + nt * 16 + m16] = acc[nt][r];
    }
  }
  __syncthreads();

  // alpha = q[dst]·(k_node[src]+e)/10 ; ex = exp(alpha); denom += ex
  if (tid < 128) {
    int el = tid >> 1, h = tid & 1;
    int s = src_s[el], d = dst_s[el];
    const unsigned short* qrow = q_b + (size_t)d * HC + h * OUT_CH;
    const unsigned short* krow = k_b + (size_t)s * HC + h * OUT_CH;
    const float* erow = e_smem + el * 209 + h * OUT_CH;
    float a = 0.f;
    for (int c = 0; c < OUT_CH; c += 4) {
      us4 q4 = *reinterpret_cast<const us4*>(qrow + c);
      us4 k4 = *reinterpret_cast<const us4*>(krow + c);
      a += b2f(q4.x) * (b2f(k4.x) + erow[c + 0]);
      a += b2f(q4.y) * (b2f(k4.y) + erow[c + 1]);
      a += b2f(q4.z) * (b2f(k4.z) + erow[c + 2]);
      a += b2f(q4.w) * (b2f(k4.w) + erow[c + 3]);
    }
    float ex = expf(a * 0.1f);   // 1/sqrt(OUT_CH); max-subtraction skipped (alpha bounded)
    exbuf[(size_t)(e0 + el) * 2 + h] = ex;
    atomicAdd(&denom[(size_t)d * 2 + h], ex);
  }

  // v_e = v_node[src] + e  (bf16 to ws)
  for (int idx = tid; idx < 64 * HC; idx += 256) {
    int el = idx / HC, c = idx % HC;
    float v = e_smem[el * 209 + c] + b2f(v_b[(size_t)src_s[el] * HC + c]);
    v_e[(size_t)(e0 + el) * HC + c] = f2b(v);
  }
}

// ---------------- final scatter: out[dst] += attn * v_e ----------------
__global__ __launch_bounds__(256) void scatter_out(
    const int* __restrict__ edge_index, const unsigned short* __restrict__ v_e,
    const float* __restrict__ exbuf, const float* __restrict__ denom,
    float* __restrict__ out)
{
  int wave = threadIdx.x >> 6, lane = threadIdx.x & 63;
  int e = blockIdx.x * 4 + wave;
  int d = edge_index[N_EDGES + e];
  float a0 = exbuf[(size_t)e * 2 + 0] / (denom[(size_t)d * 2 + 0] + 1e-16f);
  float a1 = exbuf[(size_t)e * 2 + 1] / (denom[(size_t)d * 2 + 1] + 1e-16f);
  for (int c = lane; c < HC; c += 64) {
    float v = b2f(v_e[(size_t)e * HC + c]);
    float a = (c < OUT_CH) ? a0 : a1;
    atomicAdd(&out[(size_t)d * HC + c], a * v);
  }
}

// ---------------- launch ----------------
extern "C" void kernel_launch(void* const* d_in, const int* in_sizes, int n_in,
                              void* d_out, int out_size, void* d_ws, size_t ws_size,
                              hipStream_t stream)
{
  const float* x           = (const float*)d_in[0];
  const float* last_update = (const float*)d_in[1];
  const int*   edge_index  = (const int*)  d_in[2];
  const float* t           = (const float*)d_in[3];
  const float* msg         = (const float*)d_in[4];
  const float* w_time      = (const float*)d_in[5];
  const float* b_time      = (const float*)d_in[6];
  const float* Wq = (const float*)d_in[7];  const float* bq = (const float*)d_in[8];
  const float* Wk = (const float*)d_in[9];  const float* bk = (const float*)d_in[10];
  const float* Wv = (const float*)d_in[11]; const float* bv = (const float*)d_in[12];
  const float* We = (const float*)d_in[13];
  const float* Ws = (const float*)d_in[14]; const float* bs = (const float*)d_in[15];
  float* out = (float*)d_out;

  char* ws = (char*)d_ws;
  size_t off = 0;
  auto alloc = [&](size_t bytes) -> void* {
    void* p = ws + off;
    off = (off + bytes + 255) & ~(size_t)255;
    return p;
  };
  unsigned short* W4T   = (unsigned short*)alloc((size_t)N4 * KP_NODE * 2);
  unsigned short* WeT   = (unsigned short*)alloc((size_t)NP_EDGE * KP_EDGE * 2);
  float*          bias4 = (float*)         alloc((size_t)N4 * 4);
  unsigned short* q_b   = (unsigned short*)alloc((size_t)N_NODES * HC * 2);
  unsigned short* k_b   = (unsigned short*)alloc((size_t)N_NODES * HC * 2);
  unsigned short* v_b   = (unsigned short*)alloc((size_t)N_NODES * HC * 2);
  unsigned short* v_e   = (unsigned short*)alloc((size_t)N_EDGES * HC * 2);
  float*          exbuf = (float*)         alloc((size_t)N_EDGES * 2 * 4);
  float*          denom = (float*)         alloc((size_t)N_NODES * 2 * 4);
  // total ws use ~= 285 MB

  hipMemsetAsync(denom, 0, (size_t)N_NODES * 2 * sizeof(float), stream);

  {
    int total = N4 * KP_NODE + NP_EDGE * KP_EDGE + N4;
    pack_weights<<<(total + 255) / 256, 256, 0, stream>>>(
        Wq, bq, Wk, bk, Wv, bv, We, Ws, bs, W4T, WeT, bias4);
  }
  node_gemm<<<N_NODES / 16, 256, 0, stream>>>(x, W4T, bias4, q_b, k_b, v_b, out);
  edge_gemm<<<N_EDGES / 64, 256, 0, stream>>>(
      edge_index, t, last_update, msg, w_time, b_time, WeT, q_b, k_b, v_b,
      v_e, exbuf, denom);
  scatter_out<<<N_EDGES / 4, 256, 0, stream>>>(edge_index, v_e, exbuf, denom, out);
}

// Round 2
// 1533.198 us; speedup vs baseline: 1.2135x; 1.2135x over previous
//
#include <hip/hip_runtime.h>
#include <math.h>

// ---------------- problem constants ----------------
#define N_NODES 100000
#define N_EDGES 400000
#define IN_CH   100
#define OUT_CH  100
#define HEADS   2
#define HC      200      // HEADS*OUT_CH
#define TIME_DIM 100
#define MSG_DIM  100
#define EDGE_DIM 200
// padded GEMM dims
#define KP_NODE 128      // IN_CH padded to mult of 32
#define KP_EDGE 224      // EDGE_DIM padded to mult of 32
#define NP_EDGE 208      // HC padded to mult of 16 (13 n-tiles)
#define N4      800      // 4*HC combined output cols [q|k|v|skip]
#define PAD_HC  256      // q/k rows padded: head h at h*128, cols 100..127/228..255 zero
#define EW      264      // e_lds row stride in bf16 elems (528 B)

typedef __attribute__((ext_vector_type(8))) short bf16x8_t;
typedef __attribute__((ext_vector_type(4))) float f32x4_t;

struct __align__(8) us4 { unsigned short x, y, z, w; };

static __device__ __forceinline__ float b2f(unsigned short u){
  union { float f; unsigned int i; } v; v.i = ((unsigned int)u) << 16; return v.f;
}
static __device__ __forceinline__ unsigned short f2b(float f){
  union { float f; unsigned int i; } v; v.f = f;
  unsigned int x = v.i;
  return (unsigned short)((x + 0x7fffu + ((x >> 16) & 1u)) >> 16);
}

// ---------------- pack weights (bf16, transposed so B-fragments are 16B contiguous) ----
__global__ __launch_bounds__(256) void pack_weights(
    const float* __restrict__ Wq, const float* __restrict__ bq,
    const float* __restrict__ Wk, const float* __restrict__ bk,
    const float* __restrict__ Wv, const float* __restrict__ bv,
    const float* __restrict__ We, const float* __restrict__ Ws, const float* __restrict__ bs,
    unsigned short* __restrict__ W4T, unsigned short* __restrict__ WeT,
    float* __restrict__ bias4)
{
  int idx = blockIdx.x * 256 + threadIdx.x;
  if (idx < N4 * KP_NODE) {                    // W4T[c][k], c in [0,800)
    int c = idx / KP_NODE, k = idx % KP_NODE;
    int sel = c / HC, col = c % HC;
    float v = 0.f;
    if (k < IN_CH) {
      const float* W = (sel == 0) ? Wq : (sel == 1) ? Wk : (sel == 2) ? Wv : Ws;
      v = W[k * HC + col];
    }
    W4T[idx] = f2b(v);
    return;
  }
  int j = idx - N4 * KP_NODE;
  if (j < NP_EDGE * KP_EDGE) {                 // WeT[n][k]
    int n = j / KP_EDGE, k = j % KP_EDGE;
    float v = 0.f;
    if (n < HC && k < EDGE_DIM) v = We[k * HC + n];
    WeT[j] = f2b(v);
    return;
  }
  j -= NP_EDGE * KP_EDGE;
  if (j < N4) {
    int sel = j / HC, col = j % HC;
    const float* B = (sel == 0) ? bq : (sel == 1) ? bk : (sel == 2) ? bv : bs;
    bias4[j] = B[col];
  }
}

// ---------------- node GEMM -> q_b,k_b (bf16, head-padded 256), v_b (bf16, 200), skip (fp32 out)
__global__ __launch_bounds__(256) void node_gemm(
    const float* __restrict__ x, const unsigned short* __restrict__ W4T,
    const float* __restrict__ bias4,
    unsigned short* __restrict__ q_b, unsigned short* __restrict__ k_b,
    unsigned short* __restrict__ v_b, float* __restrict__ out)
{
  __shared__ __align__(16) unsigned short x_tile[16 * 136];
  const int tid = threadIdx.x;
  const int n0 = blockIdx.x * 16;

  for (int idx = tid; idx < 16 * KP_NODE; idx += 256) {
    int r = idx >> 7, k = idx & 127;
    float v = (k < IN_CH) ? x[(n0 + r) * IN_CH + k] : 0.f;
    x_tile[r * 136 + k] = f2b(v);
  }
  __syncthreads();

  const int lane = tid & 63, wave = tid >> 6;
  const int m16 = lane & 15, quad = lane >> 4;

  f32x4_t acc[13];
  #pragma unroll
  for (int i = 0; i < 13; i++) acc[i] = (f32x4_t){0.f, 0.f, 0.f, 0.f};

  for (int kc = 0; kc < 4; kc++) {
    bf16x8_t a = *reinterpret_cast<const bf16x8_t*>(&x_tile[m16 * 136 + kc * 32 + quad * 8]);
    int i = 0;
    for (int nt = wave; nt < 50; nt += 4, i++) {
      bf16x8_t b = *reinterpret_cast<const bf16x8_t*>(
          &W4T[(nt * 16 + m16) * KP_NODE + kc * 32 + quad * 8]);
      acc[i] = __builtin_amdgcn_mfma_f32_16x16x32_bf16(a, b, acc[i], 0, 0, 0);
    }
  }

  int i = 0;
  for (int nt = wave; nt < 50; nt += 4, i++) {
    int c = nt * 16 + m16;
    float bias = bias4[c];
    #pragma unroll
    for (int r = 0; r < 4; r++) {
      int node = n0 + quad * 4 + r;
      float v = acc[i][r] + bias;
      if (c < 200) {
        int h = c / 100, cc = c % 100;
        q_b[(size_t)node * PAD_HC + h * 128 + cc] = f2b(v);
      } else if (c < 400) {
        int c2 = c - 200; int h = c2 / 100, cc = c2 % 100;
        k_b[(size_t)node * PAD_HC + h * 128 + cc] = f2b(v);
      } else if (c < 600) {
        v_b[(size_t)node * HC + (c - 400)] = f2b(v);
      } else {
        out[(size_t)node * HC + (c - 600)] = v;
      }
    }
  }
  // zero the pad columns of q_b,k_b (cols 100..127, 228..255) for the 16 nodes
  for (int idx = tid; idx < 448; idx += 256) {   // 16 nodes * 2 arrays * 2 regions * 7 us4
    int node = n0 + (idx / 28);
    int rem = idx % 28; int arr = rem / 14; int rem2 = rem % 14;
    int reg = rem2 / 7; int j = rem2 % 7;
    int col = (reg == 0 ? 100 : 228) + j * 4;
    unsigned short* p = (arr == 0 ? q_b : k_b) + (size_t)node * PAD_HC + col;
    us4 z = {0, 0, 0, 0};
    *reinterpret_cast<us4*>(p) = z;
  }
}

// ---------------- edge kernel: t_enc -> e = edge_attr@We -> alpha via MFMA diag -> exbuf, v_e
__global__ __launch_bounds__(256) void edge_gemm(
    const int* __restrict__ edge_index, const float* __restrict__ t,
    const float* __restrict__ last_update, const float* __restrict__ msg,
    const float* __restrict__ w_time, const float* __restrict__ b_time,
    const unsigned short* __restrict__ WeT,
    const unsigned short* __restrict__ q_b, const unsigned short* __restrict__ k_b,
    const unsigned short* __restrict__ v_b,
    unsigned short* __restrict__ v_e, float* __restrict__ exbuf)
{
  __shared__ __align__(16) unsigned short e_lds[64 * EW];   // 33 KB, reused ea -> e(padded)
  __shared__ int   src_s[64], dst_s[64];
  __shared__ float rel_s[64], wt_s[TIME_DIM], bt_s[TIME_DIM];

  const int tid = threadIdx.x;
  const int e0 = blockIdx.x * 64;

  if (tid < TIME_DIM) { wt_s[tid] = w_time[tid]; bt_s[tid] = b_time[tid]; }
  else if (tid >= 128 && tid < 192) {
    int el = tid - 128; int e = e0 + el;
    int s = edge_index[e], d = edge_index[N_EDGES + e];
    src_s[el] = s; dst_s[el] = d;
    rel_s[el] = fabsf(last_update[s] - t[e]);
  }
  __syncthreads();

  const int lane = tid & 63, wave = tid >> 6;
  const int m16 = lane & 15, quad = lane >> 4;
  const int r0 = wave * 16;
  unsigned short* my = e_lds + r0 * EW;

  // phase A: stage edge_attr rows r0..r0+15, cols 0..223 = [cos | msg | 0]
  for (int it = 0; it < 14; it++) {            // 16 rows * 56 us4-chunks / 64 lanes
    int idx = it * 64 + lane;
    int row = idx / 56, c4 = (idx % 56) * 4;
    us4 o;
    if (c4 < TIME_DIM) {
      float rel = rel_s[r0 + row];
      o.x = f2b(cosf(rel * wt_s[c4 + 0] + bt_s[c4 + 0]));
      o.y = f2b(cosf(rel * wt_s[c4 + 1] + bt_s[c4 + 1]));
      o.z = f2b(cosf(rel * wt_s[c4 + 2] + bt_s[c4 + 2]));
      o.w = f2b(cosf(rel * wt_s[c4 + 3] + bt_s[c4 + 3]));
    } else if (c4 < EDGE_DIM) {
      float4 m = *reinterpret_cast<const float4*>(
          msg + (size_t)(e0 + r0 + row) * MSG_DIM + (c4 - TIME_DIM));
      o.x = f2b(m.x); o.y = f2b(m.y); o.z = f2b(m.z); o.w = f2b(m.w);
    } else {
      o.x = o.y = o.z = o.w = 0;
    }
    *reinterpret_cast<us4*>(&my[row * EW + c4]) = o;
  }
  __syncthreads();

  // phase B: e = ea @ WeT   (wave's own 16 rows)
  f32x4_t acc[13];
  #pragma unroll
  for (int i = 0; i < 13; i++) acc[i] = (f32x4_t){0.f, 0.f, 0.f, 0.f};

  for (int kc = 0; kc < 7; kc++) {
    bf16x8_t a = *reinterpret_cast<const bf16x8_t*>(&my[m16 * EW + kc * 32 + quad * 8]);
    #pragma unroll
    for (int nt = 0; nt < 13; nt++) {
      bf16x8_t b = *reinterpret_cast<const bf16x8_t*>(
          &WeT[(nt * 16 + m16) * KP_EDGE + kc * 32 + quad * 8]);
      acc[nt] = __builtin_amdgcn_mfma_f32_16x16x32_bf16(a, b, acc[nt], 0, 0, 0);
    }
  }
  __syncthreads();

  // writeback e (bf16) into head-padded layout: col c -> (c<100 ? c : c+28)
  #pragma unroll
  for (int nt = 0; nt < 13; nt++) {
    int c = nt * 16 + m16;
    if (c < 200) {
      int pc = (c < 100) ? c : c + 28;
      #pragma unroll
      for (int r = 0; r < 4; r++)
        my[(quad * 4 + r) * EW + pc] = f2b(acc[nt][r]);
    }
  }
  // zero pads cols 100..127 and 228..255 of own rows
  for (int idx = lane; idx < 224; idx += 64) {  // 16 rows * 14 us4
    int row = idx / 14, j = idx % 14;
    int col = (j < 7) ? (100 + j * 4) : (228 + (j - 7) * 4);
    us4 z = {0, 0, 0, 0};
    *reinterpret_cast<us4*>(&my[row * EW + col]) = z;
  }
  __syncthreads();

  // phase C: alpha via MFMA diagonal.  D[m][n] = q[dst_m] . (k[src_n] + e_n)
  f32x4_t dacc[2];
  dacc[0] = (f32x4_t){0.f, 0.f, 0.f, 0.f};
  dacc[1] = (f32x4_t){0.f, 0.f, 0.f, 0.f};
  const int my_src = src_s[r0 + m16];
  const int my_dst = dst_s[r0 + m16];
  #pragma unroll
  for (int h = 0; h < 2; h++) {
    #pragma unroll
    for (int kc = 0; kc < 4; kc++) {
      int ko = h * 128 + kc * 32 + quad * 8;
      bf16x8_t a  = *reinterpret_cast<const bf16x8_t*>(&q_b[(size_t)my_dst * PAD_HC + ko]);
      bf16x8_t kb = *reinterpret_cast<const bf16x8_t*>(&k_b[(size_t)my_src * PAD_HC + ko]);
      bf16x8_t eb = *reinterpret_cast<const bf16x8_t*>(&my[m16 * EW + ko]);
      dacc[h] = __builtin_amdgcn_mfma_f32_16x16x32_bf16(a, kb, dacc[h], 0, 0, 0);
      dacc[h] = __builtin_amdgcn_mfma_f32_16x16x32_bf16(a, eb, dacc[h], 0, 0, 0);
    }
  }
  if (quad == (m16 >> 2)) {
    int r = m16 & 3;
    int e = e0 + r0 + m16;
    exbuf[(size_t)e * 2 + 0] = expf(dacc[0][r] * 0.1f);
    exbuf[(size_t)e * 2 + 1] = expf(dacc[1][r] * 0.1f);
  }

  // phase D: v_e = v_b[src] + e   (compact 200 cols, bf16)
  for (int idx = lane; idx < 800; idx += 64) {  // 16 rows * 50 us4
    int row = idx / 50, c = (idx % 50) * 4;
    int pc = (c < 100) ? c : c + 28;
    us4 ev = *reinterpret_cast<const us4*>(&my[row * EW + pc]);
    us4 vv = *reinterpret_cast<const us4*>(&v_b[(size_t)src_s[r0 + row] * HC + c]);
    us4 o;
    o.x = f2b(b2f(ev.x) + b2f(vv.x));
    o.y = f2b(b2f(ev.y) + b2f(vv.y));
    o.z = f2b(b2f(ev.z) + b2f(vv.z));
    o.w = f2b(b2f(ev.w) + b2f(vv.w));
    *reinterpret_cast<us4*>(&v_e[(size_t)(e0 + r0 + row) * HC + c]) = o;
  }
}

// ---------------- CSR build ----------------
__global__ __launch_bounds__(256) void hist_kernel(const int* __restrict__ edge_index,
                                                   int* __restrict__ deg)
{
  int e = blockIdx.x * 256 + threadIdx.x;
  if (e < N_EDGES) atomicAdd(&deg[edge_index[N_EDGES + e]], 1);
}

__global__ __launch_bounds__(256) void scan1(const int* __restrict__ deg,
                                             int* __restrict__ cursor, int* __restrict__ bsum)
{
  __shared__ int s[256];
  const int tid = threadIdx.x;
  const int base = blockIdx.x * 1024 + tid * 4;
  int v[4]; int sum = 0;
  #pragma unroll
  for (int j = 0; j < 4; j++) {
    int i = base + j;
    v[j] = (i < N_NODES) ? deg[i] : 0;
    sum += v[j];
  }
  s[tid] = sum; __syncthreads();
  for (int d = 1; d < 256; d <<= 1) {
    int y = (tid >= d) ? s[tid - d] : 0;
    __syncthreads();
    s[tid] += y;
    __syncthreads();
  }
  int excl = s[tid] - sum;
  if (tid == 255) bsum[blockIdx.x] = s[255];
  int run = excl;
  #pragma unroll
  for (int j = 0; j < 4; j++) {
    int i = base + j;
    if (i < N_NODES) cursor[i] = run;
    run += v[j];
  }
}

__global__ void scan2(int* __restrict__ bsum, int nb)
{
  if (threadIdx.x == 0) {
    int acc = 0;
    for (int i = 0; i < nb; i++) { int t = bsum[i]; bsum[i] = acc; acc += t; }
  }
}

__global__ __launch_bounds__(256) void scan3(int* __restrict__ cursor,
                                             const int* __restrict__ bsum)
{
  int i = blockIdx.x * 256 + threadIdx.x;
  if (i < N_NODES) cursor[i] += bsum[i >> 10];
}

__global__ __launch_bounds__(256) void fill_csr(const int* __restrict__ edge_index,
                                                int* __restrict__ cursor, int* __restrict__ csr)
{
  int e = blockIdx.x * 256 + threadIdx.x;
  if (e < N_EDGES) {
    int p = atomicAdd(&cursor[edge_index[N_EDGES + e]], 1);
    csr[p] = e;
  }
}

// ---------------- gather: out[n] = skip + sum_e attn * v_e  (one wave per node) --------
__global__ __launch_bounds__(256) void gather_out(
    const int* __restrict__ cursor /* = end offsets after fill */,
    const int* __restrict__ deg, const int* __restrict__ csr,
    const unsigned short* __restrict__ v_e, const float* __restrict__ exbuf,
    float* __restrict__ out)
{
  const int wave = threadIdx.x >> 6, lane = threadIdx.x & 63;
  const int n = blockIdx.x * 4 + wave;
  const int dg = deg[n];
  const int off = cursor[n] - dg;          // start offset (fill advanced cursor by dg)

  float d0 = 1e-16f, d1 = 1e-16f;
  for (int j = 0; j < dg; j++) {
    int e = csr[off + j];
    d0 += exbuf[(size_t)e * 2 + 0];
    d1 += exbuf[(size_t)e * 2 + 1];
  }
  const float i0 = 1.f / d0, i1 = 1.f / d1;

  const int c0 = lane, c1 = lane + 64, c2 = lane + 128, c3 = lane + 192;
  float a0 = 0.f, a1 = 0.f, a2 = 0.f, a3 = 0.f;
  for (int j = 0; j < dg; j++) {
    int e = csr[off + j];
    float w0 = exbuf[(size_t)e * 2 + 0] * i0;
    float w1 = exbuf[(size_t)e * 2 + 1] * i1;
    const unsigned short* vr = v_e + (size_t)e * HC;
    a0 += ((c0 < 100) ? w0 : w1) * b2f(vr[c0]);
    a1 += ((c1 < 100) ? w0 : w1) * b2f(vr[c1]);
    a2 += w1 * b2f(vr[c2]);
    if (c3 < HC) a3 += w1 * b2f(vr[c3]);
  }
  float* o = out + (size_t)n * HC;
  o[c0] += a0; o[c1] += a1; o[c2] += a2;
  if (c3 < HC) o[c3] += a3;
}

// ---------------- launch ----------------
extern "C" void kernel_launch(void* const* d_in, const int* in_sizes, int n_in,
                              void* d_out, int out_size, void* d_ws, size_t ws_size,
                              hipStream_t stream)
{
  const float* x           = (const float*)d_in[0];
  const float* last_update = (const float*)d_in[1];
  const int*   edge_index  = (const int*)  d_in[2];
  const float* t           = (const float*)d_in[3];
  const float* msg         = (const float*)d_in[4];
  const float* w_time      = (const float*)d_in[5];
  const float* b_time      = (const float*)d_in[6];
  const float* Wq = (const float*)d_in[7];  const float* bq = (const float*)d_in[8];
  const float* Wk = (const float*)d_in[9];  const float* bk = (const float*)d_in[10];
  const float* Wv = (const float*)d_in[11]; const float* bv = (const float*)d_in[12];
  const float* We = (const float*)d_in[13];
  const float* Ws = (const float*)d_in[14]; const float* bs = (const float*)d_in[15];
  float* out = (float*)d_out;

  char* ws = (char*)d_ws;
  size_t off = 0;
  auto alloc = [&](size_t bytes) -> void* {
    void* p = ws + off;
    off = (off + bytes + 255) & ~(size_t)255;
    return p;
  };
  unsigned short* W4T   = (unsigned short*)alloc((size_t)N4 * KP_NODE * 2);
  unsigned short* WeT   = (unsigned short*)alloc((size_t)NP_EDGE * KP_EDGE * 2);
  float*          bias4 = (float*)         alloc((size_t)N4 * 4);
  unsigned short* q_b   = (unsigned short*)alloc((size_t)N_NODES * PAD_HC * 2);
  unsigned short* k_b   = (unsigned short*)alloc((size_t)N_NODES * PAD_HC * 2);
  unsigned short* v_b   = (unsigned short*)alloc((size_t)N_NODES * HC * 2);
  unsigned short* v_e   = (unsigned short*)alloc((size_t)N_EDGES * HC * 2);
  float*          exbuf = (float*)         alloc((size_t)N_EDGES * 2 * 4);
  int*            deg   = (int*)           alloc((size_t)N_NODES * 4);
  int*            cursor= (int*)           alloc((size_t)N_NODES * 4);
  int*            bsum  = (int*)           alloc((size_t)128 * 4);
  int*            csr   = (int*)           alloc((size_t)N_EDGES * 4);
  // total ws use ~= 310 MB

  hipMemsetAsync(deg, 0, (size_t)N_NODES * 4, stream);

  {
    int total = N4 * KP_NODE + NP_EDGE * KP_EDGE + N4;
    pack_weights<<<(total + 255) / 256, 256, 0, stream>>>(
        Wq, bq, Wk, bk, Wv, bv, We, Ws, bs, W4T, WeT, bias4);
  }
  hist_kernel<<<(N_EDGES + 255) / 256, 256, 0, stream>>>(edge_index, deg);
  const int nb = (N_NODES + 1023) / 1024;   // 98
  scan1<<<nb, 256, 0, stream>>>(deg, cursor, bsum);
  scan2<<<1, 64, 0, stream>>>(bsum, nb);
  scan3<<<(N_NODES + 255) / 256, 256, 0, stream>>>(cursor, bsum);

  node_gemm<<<N_NODES / 16, 256, 0, stream>>>(x, W4T, bias4, q_b, k_b, v_b, out);
  edge_gemm<<<N_EDGES / 64, 256, 0, stream>>>(
      edge_index, t, last_update, msg, w_time, b_time, WeT, q_b, k_b, v_b,
      v_e, exbuf);
  fill_csr<<<(N_EDGES + 255) / 256, 256, 0, stream>>>(edge_index, cursor, csr);
  gather_out<<<N_NODES / 4, 256, 0, stream>>>(cursor, deg, csr, v_e, exbuf, out);
}

// Round 3
// 1461.098 us; speedup vs baseline: 1.2734x; 1.0493x over previous
//
#include <hip/hip_runtime.h>
#include <math.h>

// ---------------- problem constants ----------------
#define N_NODES 100000
#define N_EDGES 400000
#define IN_CH   100
#define OUT_CH  100
#define HEADS   2
#define HC      200      // HEADS*OUT_CH
#define TIME_DIM 100
#define MSG_DIM  100
#define EDGE_DIM 200
// padded GEMM dims
#define KP_NODE 128      // IN_CH padded to mult of 32
#define KP_EDGE 224      // EDGE_DIM padded to mult of 32
#define NP_EDGE 208      // HC padded to mult of 16 (13 n-tiles)
#define N4      800      // 4*HC combined output cols [q|k|v|skip]
#define PAD_HC  256      // q/k rows padded: head h at h*128, cols 100..127/228..255 zero
#define EW      264      // e_lds row stride in bf16 elems (528 B)

typedef __attribute__((ext_vector_type(8))) short bf16x8_t;
typedef __attribute__((ext_vector_type(4))) float f32x4_t;

struct __align__(8) us4 { unsigned short x, y, z, w; };

static __device__ __forceinline__ float b2f(unsigned short u){
  union { float f; unsigned int i; } v; v.i = ((unsigned int)u) << 16; return v.f;
}
static __device__ __forceinline__ unsigned short f2b(float f){
  union { float f; unsigned int i; } v; v.f = f;
  unsigned int x = v.i;
  return (unsigned short)((x + 0x7fffu + ((x >> 16) & 1u)) >> 16);
}

// ---------------- pack weights (bf16, transposed so B-fragments are 16B contiguous) ----
__global__ __launch_bounds__(256) void pack_weights(
    const float* __restrict__ Wq, const float* __restrict__ bq,
    const float* __restrict__ Wk, const float* __restrict__ bk,
    const float* __restrict__ Wv, const float* __restrict__ bv,
    const float* __restrict__ We, const float* __restrict__ Ws, const float* __restrict__ bs,
    unsigned short* __restrict__ W4T, unsigned short* __restrict__ WeT,
    float* __restrict__ bias4)
{
  int idx = blockIdx.x * 256 + threadIdx.x;
  if (idx < N4 * KP_NODE) {                    // W4T[c][k], c in [0,800)
    int c = idx / KP_NODE, k = idx % KP_NODE;
    int sel = c / HC, col = c % HC;
    float v = 0.f;
    if (k < IN_CH) {
      const float* W = (sel == 0) ? Wq : (sel == 1) ? Wk : (sel == 2) ? Wv : Ws;
      v = W[k * HC + col];
    }
    W4T[idx] = f2b(v);
    return;
  }
  int j = idx - N4 * KP_NODE;
  if (j < NP_EDGE * KP_EDGE) {                 // WeT[n][k]
    int n = j / KP_EDGE, k = j % KP_EDGE;
    float v = 0.f;
    if (n < HC && k < EDGE_DIM) v = We[k * HC + n];
    WeT[j] = f2b(v);
    return;
  }
  j -= NP_EDGE * KP_EDGE;
  if (j < N4) {
    int sel = j / HC, col = j % HC;
    const float* B = (sel == 0) ? bq : (sel == 1) ? bk : (sel == 2) ? bv : bs;
    bias4[j] = B[col];
  }
}

// ---------------- node GEMM: 32 nodes/block, LDS-staged coalesced epilogue ----------------
// waves own contiguous col ranges: w0: nt 0..12, w1: 13..25, w2: 26..37, w3: 38..49
__global__ __launch_bounds__(256) void node_gemm(
    const float* __restrict__ x, const unsigned short* __restrict__ W4T,
    const float* __restrict__ bias4,
    unsigned short* __restrict__ q_b, unsigned short* __restrict__ k_b,
    unsigned short* __restrict__ v_b, float* __restrict__ out)
{
  __shared__ __align__(16) unsigned char smem[25600];  // union: x_tile | stage buffers
  unsigned short* xt = (unsigned short*)smem;          // [32][136] bf16 = 8704 B

  const int tid = threadIdx.x;
  const int n0 = blockIdx.x * 32;

  // load x tile (float4, rows 400 B) + zero pad cols 100..127
  for (int idx = tid; idx < 800; idx += 256) {
    int r = idx / 25, j = (idx % 25) * 4;
    float4 xv = *reinterpret_cast<const float4*>(x + (size_t)(n0 + r) * IN_CH + j);
    unsigned short* dst = xt + r * 136 + j;
    dst[0] = f2b(xv.x); dst[1] = f2b(xv.y); dst[2] = f2b(xv.z); dst[3] = f2b(xv.w);
  }
  for (int idx = tid; idx < 224; idx += 256) {   // 32 rows * 7 us4
    int r = idx / 7, j = idx % 7;
    us4 z = {0, 0, 0, 0};
    *reinterpret_cast<us4*>(&xt[r * 136 + 100 + j * 4]) = z;
  }
  __syncthreads();

  const int lane = tid & 63, wave = tid >> 6;
  const int m16 = lane & 15, quad = lane >> 4;
  const int base = (wave < 2) ? wave * 13 : 26 + (wave - 2) * 12;
  const int cnt  = (wave < 2) ? 13 : 12;

  f32x4_t acc[2][13];
  #pragma unroll
  for (int s = 0; s < 2; s++)
    #pragma unroll
    for (int i = 0; i < 13; i++) acc[s][i] = (f32x4_t){0.f, 0.f, 0.f, 0.f};

  for (int kc = 0; kc < 4; kc++) {
    bf16x8_t a0 = *reinterpret_cast<const bf16x8_t*>(&xt[m16 * 136 + kc * 32 + quad * 8]);
    bf16x8_t a1 = *reinterpret_cast<const bf16x8_t*>(&xt[(m16 + 16) * 136 + kc * 32 + quad * 8]);
    for (int i = 0; i < cnt; i++) {
      bf16x8_t b = *reinterpret_cast<const bf16x8_t*>(
          &W4T[(size_t)((base + i) * 16 + m16) * KP_NODE + kc * 32 + quad * 8]);
      acc[0][i] = __builtin_amdgcn_mfma_f32_16x16x32_bf16(a0, b, acc[0][i], 0, 0, 0);
      acc[1][i] = __builtin_amdgcn_mfma_f32_16x16x32_bf16(a1, b, acc[1][i], 0, 0, 0);
    }
  }
  __syncthreads();   // x_tile dead; smem becomes staging

  unsigned short* stg = (unsigned short*)smem;
  float*          stgf = (float*)smem;

  // ---- pass 1: q (cols 0..199 -> head-padded [32][256]) ----
  {
    for (int idx = tid; idx < 448; idx += 256) {  // zero pads: 32 rows * 14 us4
      int r = idx / 14, j = idx % 14;
      int col = (j < 7) ? (100 + j * 4) : (228 + (j - 7) * 4);
      us4 z = {0, 0, 0, 0};
      *reinterpret_cast<us4*>(&stg[r * 256 + col]) = z;
    }
    for (int s = 0; s < 2; s++)
      for (int i = 0; i < cnt; i++) {
        int c = (base + i) * 16 + m16;
        if (c < 200) {
          int pc = (c < 100) ? c : c + 28;
          float bias = bias4[c];
          #pragma unroll
          for (int r = 0; r < 4; r++)
            stg[(s * 16 + quad * 4 + r) * 256 + pc] = f2b(acc[s][i][r] + bias);
        }
      }
    __syncthreads();
    uint4* gq = (uint4*)(q_b + (size_t)n0 * PAD_HC);
    for (int idx = tid; idx < 1024; idx += 256)   // 16 KB linear
      gq[idx] = ((const uint4*)stg)[idx];
    __syncthreads();
  }
  // ---- pass 2: k (cols 200..399) ----
  {
    for (int idx = tid; idx < 448; idx += 256) {
      int r = idx / 14, j = idx % 14;
      int col = (j < 7) ? (100 + j * 4) : (228 + (j - 7) * 4);
      us4 z = {0, 0, 0, 0};
      *reinterpret_cast<us4*>(&stg[r * 256 + col]) = z;
    }
    for (int s = 0; s < 2; s++)
      for (int i = 0; i < cnt; i++) {
        int c = (base + i) * 16 + m16;
        if (c >= 200 && c < 400) {
          int cc = c - 200;
          int pc = (cc < 100) ? cc : cc + 28;
          float bias = bias4[c];
          #pragma unroll
          for (int r = 0; r < 4; r++)
            stg[(s * 16 + quad * 4 + r) * 256 + pc] = f2b(acc[s][i][r] + bias);
        }
      }
    __syncthreads();
    uint4* gk = (uint4*)(k_b + (size_t)n0 * PAD_HC);
    for (int idx = tid; idx < 1024; idx += 256)
      gk[idx] = ((const uint4*)stg)[idx];
    __syncthreads();
  }
  // ---- pass 3: v (cols 400..599 -> compact [32][200]) ----
  {
    for (int s = 0; s < 2; s++)
      for (int i = 0; i < cnt; i++) {
        int c = (base + i) * 16 + m16;
        if (c >= 400 && c < 600) {
          int cc = c - 400;
          float bias = bias4[c];
          #pragma unroll
          for (int r = 0; r < 4; r++)
            stg[(s * 16 + quad * 4 + r) * 200 + cc] = f2b(acc[s][i][r] + bias);
        }
      }
    __syncthreads();
    uint4* gv = (uint4*)(v_b + (size_t)n0 * HC);
    for (int idx = tid; idx < 800; idx += 256)    // 12.8 KB linear
      gv[idx] = ((const uint4*)stg)[idx];
    __syncthreads();
  }
  // ---- pass 4: skip/out (cols 600..799 -> fp32 [32][200]) ----
  {
    for (int s = 0; s < 2; s++)
      for (int i = 0; i < cnt; i++) {
        int c = (base + i) * 16 + m16;
        if (c >= 600) {
          int cc = c - 600;
          float bias = bias4[c];
          #pragma unroll
          for (int r = 0; r < 4; r++)
            stgf[(s * 16 + quad * 4 + r) * 200 + cc] = acc[s][i][r] + bias;
        }
      }
    __syncthreads();
    uint4* go = (uint4*)(out + (size_t)n0 * HC);
    for (int idx = tid; idx < 1600; idx += 256)   // 25.6 KB linear
      go[idx] = ((const uint4*)stgf)[idx];
  }
}

// ---------------- edge kernel: t_enc -> e = edge_attr@We -> alpha via MFMA diag -> exbuf, v_e
__global__ __launch_bounds__(256) void edge_gemm(
    const int* __restrict__ edge_index, const float* __restrict__ t,
    const float* __restrict__ last_update, const float* __restrict__ msg,
    const float* __restrict__ w_time, const float* __restrict__ b_time,
    const unsigned short* __restrict__ WeT,
    const unsigned short* __restrict__ q_b, const unsigned short* __restrict__ k_b,
    const unsigned short* __restrict__ v_b,
    unsigned short* __restrict__ v_e, float* __restrict__ exbuf)
{
  __shared__ __align__(16) unsigned short e_lds[64 * EW];   // 33 KB, reused ea -> e(padded)
  __shared__ int   src_s[64], dst_s[64];
  __shared__ float rel_s[64], wt_s[TIME_DIM], bt_s[TIME_DIM];

  const int tid = threadIdx.x;
  const int e0 = blockIdx.x * 64;

  if (tid < TIME_DIM) { wt_s[tid] = w_time[tid]; bt_s[tid] = b_time[tid]; }
  else if (tid >= 128 && tid < 192) {
    int el = tid - 128; int e = e0 + el;
    int s = edge_index[e], d = edge_index[N_EDGES + e];
    src_s[el] = s; dst_s[el] = d;
    rel_s[el] = fabsf(last_update[s] - t[e]);
  }
  __syncthreads();

  const int lane = tid & 63, wave = tid >> 6;
  const int m16 = lane & 15, quad = lane >> 4;
  const int r0 = wave * 16;
  unsigned short* my = e_lds + r0 * EW;

  // phase A: stage edge_attr rows r0..r0+15, cols 0..223 = [cos | msg | 0]
  for (int it = 0; it < 14; it++) {            // 16 rows * 56 us4-chunks / 64 lanes
    int idx = it * 64 + lane;
    int row = idx / 56, c4 = (idx % 56) * 4;
    us4 o;
    if (c4 < TIME_DIM) {
      float rel = rel_s[r0 + row];
      o.x = f2b(cosf(rel * wt_s[c4 + 0] + bt_s[c4 + 0]));
      o.y = f2b(cosf(rel * wt_s[c4 + 1] + bt_s[c4 + 1]));
      o.z = f2b(cosf(rel * wt_s[c4 + 2] + bt_s[c4 + 2]));
      o.w = f2b(cosf(rel * wt_s[c4 + 3] + bt_s[c4 + 3]));
    } else if (c4 < EDGE_DIM) {
      float4 m = *reinterpret_cast<const float4*>(
          msg + (size_t)(e0 + r0 + row) * MSG_DIM + (c4 - TIME_DIM));
      o.x = f2b(m.x); o.y = f2b(m.y); o.z = f2b(m.z); o.w = f2b(m.w);
    } else {
      o.x = o.y = o.z = o.w = 0;
    }
    *reinterpret_cast<us4*>(&my[row * EW + c4]) = o;
  }
  __syncthreads();

  // phase B: e = ea @ WeT   (wave's own 16 rows)
  f32x4_t acc[13];
  #pragma unroll
  for (int i = 0; i < 13; i++) acc[i] = (f32x4_t){0.f, 0.f, 0.f, 0.f};

  for (int kc = 0; kc < 7; kc++) {
    bf16x8_t a = *reinterpret_cast<const bf16x8_t*>(&my[m16 * EW + kc * 32 + quad * 8]);
    #pragma unroll
    for (int nt = 0; nt < 13; nt++) {
      bf16x8_t b = *reinterpret_cast<const bf16x8_t*>(
          &WeT[(nt * 16 + m16) * KP_EDGE + kc * 32 + quad * 8]);
      acc[nt] = __builtin_amdgcn_mfma_f32_16x16x32_bf16(a, b, acc[nt], 0, 0, 0);
    }
  }
  __syncthreads();

  // writeback e (bf16) into head-padded layout: col c -> (c<100 ? c : c+28)
  #pragma unroll
  for (int nt = 0; nt < 13; nt++) {
    int c = nt * 16 + m16;
    if (c < 200) {
      int pc = (c < 100) ? c : c + 28;
      #pragma unroll
      for (int r = 0; r < 4; r++)
        my[(quad * 4 + r) * EW + pc] = f2b(acc[nt][r]);
    }
  }
  // zero pads cols 100..127 and 228..255 of own rows
  for (int idx = lane; idx < 224; idx += 64) {  // 16 rows * 14 us4
    int row = idx / 14, j = idx % 14;
    int col = (j < 7) ? (100 + j * 4) : (228 + (j - 7) * 4);
    us4 z = {0, 0, 0, 0};
    *reinterpret_cast<us4*>(&my[row * EW + col]) = z;
  }
  __syncthreads();

  // phase C: alpha via MFMA diagonal.  D[m][n] = q[dst_m] . (k[src_n] + e_n)
  f32x4_t dacc[2];
  dacc[0] = (f32x4_t){0.f, 0.f, 0.f, 0.f};
  dacc[1] = (f32x4_t){0.f, 0.f, 0.f, 0.f};
  const int my_src = src_s[r0 + m16];
  const int my_dst = dst_s[r0 + m16];
  #pragma unroll
  for (int h = 0; h < 2; h++) {
    #pragma unroll
    for (int kc = 0; kc < 4; kc++) {
      int ko = h * 128 + kc * 32 + quad * 8;
      bf16x8_t a  = *reinterpret_cast<const bf16x8_t*>(&q_b[(size_t)my_dst * PAD_HC + ko]);
      bf16x8_t kb = *reinterpret_cast<const bf16x8_t*>(&k_b[(size_t)my_src * PAD_HC + ko]);
      bf16x8_t eb = *reinterpret_cast<const bf16x8_t*>(&my[m16 * EW + ko]);
      dacc[h] = __builtin_amdgcn_mfma_f32_16x16x32_bf16(a, kb, dacc[h], 0, 0, 0);
      dacc[h] = __builtin_amdgcn_mfma_f32_16x16x32_bf16(a, eb, dacc[h], 0, 0, 0);
    }
  }
  if (quad == (m16 >> 2)) {
    int r = m16 & 3;
    int e = e0 + r0 + m16;
    exbuf[(size_t)e * 2 + 0] = expf(dacc[0][r] * 0.1f);
    exbuf[(size_t)e * 2 + 1] = expf(dacc[1][r] * 0.1f);
  }

  // phase D: v_e = v_b[src] + e   (compact 200 cols, bf16)
  for (int idx = lane; idx < 800; idx += 64) {  // 16 rows * 50 us4
    int row = idx / 50, c = (idx % 50) * 4;
    int pc = (c < 100) ? c : c + 28;
    us4 ev = *reinterpret_cast<const us4*>(&my[row * EW + pc]);
    us4 vv = *reinterpret_cast<const us4*>(&v_b[(size_t)src_s[r0 + row] * HC + c]);
    us4 o;
    o.x = f2b(b2f(ev.x) + b2f(vv.x));
    o.y = f2b(b2f(ev.y) + b2f(vv.y));
    o.z = f2b(b2f(ev.z) + b2f(vv.z));
    o.w = f2b(b2f(ev.w) + b2f(vv.w));
    *reinterpret_cast<us4*>(&v_e[(size_t)(e0 + r0 + row) * HC + c]) = o;
  }
}

// ---------------- CSR build ----------------
__global__ __launch_bounds__(256) void hist_kernel(const int* __restrict__ edge_index,
                                                   int* __restrict__ deg)
{
  int e = blockIdx.x * 256 + threadIdx.x;
  if (e < N_EDGES) atomicAdd(&deg[edge_index[N_EDGES + e]], 1);
}

__global__ __launch_bounds__(256) void scan1(const int* __restrict__ deg,
                                             int* __restrict__ cursor, int* __restrict__ bsum)
{
  __shared__ int s[256];
  const int tid = threadIdx.x;
  const int base = blockIdx.x * 1024 + tid * 4;
  int v[4]; int sum = 0;
  #pragma unroll
  for (int j = 0; j < 4; j++) {
    int i = base + j;
    v[j] = (i < N_NODES) ? deg[i] : 0;
    sum += v[j];
  }
  s[tid] = sum; __syncthreads();
  for (int d = 1; d < 256; d <<= 1) {
    int y = (tid >= d) ? s[tid - d] : 0;
    __syncthreads();
    s[tid] += y;
    __syncthreads();
  }
  int excl = s[tid] - sum;
  if (tid == 255) bsum[blockIdx.x] = s[255];
  int run = excl;
  #pragma unroll
  for (int j = 0; j < 4; j++) {
    int i = base + j;
    if (i < N_NODES) cursor[i] = run;
    run += v[j];
  }
}

__global__ void scan2(int* __restrict__ bsum, int nb)
{
  if (threadIdx.x == 0) {
    int acc = 0;
    for (int i = 0; i < nb; i++) { int t = bsum[i]; bsum[i] = acc; acc += t; }
  }
}

__global__ __launch_bounds__(256) void scan3(int* __restrict__ cursor,
                                             const int* __restrict__ bsum)
{
  int i = blockIdx.x * 256 + threadIdx.x;
  if (i < N_NODES) cursor[i] += bsum[i >> 10];
}

__global__ __launch_bounds__(256) void fill_csr(const int* __restrict__ edge_index,
                                                int* __restrict__ cursor, int* __restrict__ csr)
{
  int e = blockIdx.x * 256 + threadIdx.x;
  if (e < N_EDGES) {
    int p = atomicAdd(&cursor[edge_index[N_EDGES + e]], 1);
    csr[p] = e;
  }
}

// ---------------- gather: out[n] = skip + sum_e attn * v_e  (one wave per node) --------
__global__ __launch_bounds__(256) void gather_out(
    const int* __restrict__ cursor /* = end offsets after fill */,
    const int* __restrict__ deg, const int* __restrict__ csr,
    const unsigned short* __restrict__ v_e, const float* __restrict__ exbuf,
    float* __restrict__ out)
{
  const int wave = threadIdx.x >> 6, lane = threadIdx.x & 63;
  const int n = blockIdx.x * 4 + wave;
  const int dg = deg[n];
  const int off = cursor[n] - dg;          // start offset (fill advanced cursor by dg)

  float d0 = 1e-16f, d1 = 1e-16f;
  for (int j = 0; j < dg; j++) {
    int e = csr[off + j];
    d0 += exbuf[(size_t)e * 2 + 0];
    d1 += exbuf[(size_t)e * 2 + 1];
  }
  const float i0 = 1.f / d0, i1 = 1.f / d1;

  const int c0 = lane, c1 = lane + 64, c2 = lane + 128, c3 = lane + 192;
  float a0 = 0.f, a1 = 0.f, a2 = 0.f, a3 = 0.f;
  for (int j = 0; j < dg; j++) {
    int e = csr[off + j];
    float w0 = exbuf[(size_t)e * 2 + 0] * i0;
    float w1 = exbuf[(size_t)e * 2 + 1] * i1;
    const unsigned short* vr = v_e + (size_t)e * HC;
    a0 += ((c0 < 100) ? w0 : w1) * b2f(vr[c0]);
    a1 += ((c1 < 100) ? w0 : w1) * b2f(vr[c1]);
    a2 += w1 * b2f(vr[c2]);
    if (c3 < HC) a3 += w1 * b2f(vr[c3]);
  }
  float* o = out + (size_t)n * HC;
  o[c0] += a0; o[c1] += a1; o[c2] += a2;
  if (c3 < HC) o[c3] += a3;
}

// ---------------- launch ----------------
extern "C" void kernel_launch(void* const* d_in, const int* in_sizes, int n_in,
                              void* d_out, int out_size, void* d_ws, size_t ws_size,
                              hipStream_t stream)
{
  const float* x           = (const float*)d_in[0];
  const float* last_update = (const float*)d_in[1];
  const int*   edge_index  = (const int*)  d_in[2];
  const float* t           = (const float*)d_in[3];
  const float* msg         = (const float*)d_in[4];
  const float* w_time      = (const float*)d_in[5];
  const float* b_time      = (const float*)d_in[6];
  const float* Wq = (const float*)d_in[7];  const float* bq = (const float*)d_in[8];
  const float* Wk = (const float*)d_in[9];  const float* bk = (const float*)d_in[10];
  const float* Wv = (const float*)d_in[11]; const float* bv = (const float*)d_in[12];
  const float* We = (const float*)d_in[13];
  const float* Ws = (const float*)d_in[14]; const float* bs = (const float*)d_in[15];
  float* out = (float*)d_out;

  char* ws = (char*)d_ws;
  size_t off = 0;
  auto alloc = [&](size_t bytes) -> void* {
    void* p = ws + off;
    off = (off + bytes + 255) & ~(size_t)255;
    return p;
  };
  unsigned short* W4T   = (unsigned short*)alloc((size_t)N4 * KP_NODE * 2);
  unsigned short* WeT   = (unsigned short*)alloc((size_t)NP_EDGE * KP_EDGE * 2);
  float*          bias4 = (float*)         alloc((size_t)N4 * 4);
  unsigned short* q_b   = (unsigned short*)alloc((size_t)N_NODES * PAD_HC * 2);
  unsigned short* k_b   = (unsigned short*)alloc((size_t)N_NODES * PAD_HC * 2);
  unsigned short* v_b   = (unsigned short*)alloc((size_t)N_NODES * HC * 2);
  unsigned short* v_e   = (unsigned short*)alloc((size_t)N_EDGES * HC * 2);
  float*          exbuf = (float*)         alloc((size_t)N_EDGES * 2 * 4);
  int*            deg   = (int*)           alloc((size_t)N_NODES * 4);
  int*            cursor= (int*)           alloc((size_t)N_NODES * 4);
  int*            bsum  = (int*)           alloc((size_t)128 * 4);
  int*            csr   = (int*)           alloc((size_t)N_EDGES * 4);
  // total ws use ~= 310 MB

  hipMemsetAsync(deg, 0, (size_t)N_NODES * 4, stream);

  {
    int total = N4 * KP_NODE + NP_EDGE * KP_EDGE + N4;
    pack_weights<<<(total + 255) / 256, 256, 0, stream>>>(
        Wq, bq, Wk, bk, Wv, bv, We, Ws, bs, W4T, WeT, bias4);
  }
  hist_kernel<<<(N_EDGES + 255) / 256, 256, 0, stream>>>(edge_index, deg);
  const int nb = (N_NODES + 1023) / 1024;   // 98
  scan1<<<nb, 256, 0, stream>>>(deg, cursor, bsum);
  scan2<<<1, 64, 0, stream>>>(bsum, nb);
  scan3<<<(N_NODES + 255) / 256, 256, 0, stream>>>(cursor, bsum);

  node_gemm<<<N_NODES / 32, 256, 0, stream>>>(x, W4T, bias4, q_b, k_b, v_b, out);
  edge_gemm<<<N_EDGES / 64, 256, 0, stream>>>(
      edge_index, t, last_update, msg, w_time, b_time, WeT, q_b, k_b, v_b,
      v_e, exbuf);
  fill_csr<<<(N_EDGES + 255) / 256, 256, 0, stream>>>(edge_index, cursor, csr);
  gather_out<<<N_NODES / 4, 256, 0, stream>>>(cursor, deg, csr, v_e, exbuf, out);
}